// Round 13
// baseline (96.326 us; speedup 1.0000x reference)
//
#include <hip/hip_runtime.h>

// SVF cascade frequency response on MI355X (gfx950) — R12.
//
// H(x) = (1+1j) * prod_k (b0*x^2+b1*x+b2)/(a0*x^2+a1*x+a2)
//
// Established: PLANAR output [Re H | Im H]; f32 datapath, octic fusion
// (4 sections/stage, 16 stages, coefs f64-exact -> f32), scalar-path coef
// delivery via d_ws, per-stage division w/ raw v_rcp_f32, guarded stores.
// R11 absmax bit-equal to f64 runs (3.814697e-6 = np ref's own f32 noise).
//
// Bench anatomy: 82.3 us = 41 (harness 268MB poison fill, 82% HBM peak,
// untouchable) + ~18 (restore/launch) + ~22 (main kernel). Kernel op floor
// ~10.6 us -> issue efficiency ~55%. R12 attacks per-wave ILP: MPT 2 -> 4
// (bit-identical per-sample math, 4 independent chains/wave, coef s_loads
// amortized 2x). Predict kernel ~15 us, bench ~74-78.

#define NSEC  64
#define NOCT  16
#define BLOCK 256
#define MPT   4    // samples per thread

// Pre-kernel: octic (4-section fused) coefficients in f64, stored f32.
// Layout: coef[t*18 + 0..8] = num e0..e8 (x^8..x^0), [9..17] = den e0..e8.
__global__ __launch_bounds__(64) void svf_coef_v12(
    const float* __restrict__ f_g,  const float* __restrict__ R_g,
    const float* __restrict__ lp_g, const float* __restrict__ bp_g,
    const float* __restrict__ hp_g,
    float* __restrict__ coef)
{
    const int t = threadIdx.x;
    if (t >= NOCT) return;

    double qn[2][5], qd[2][5];   // two quartics (pairs of sections)
    for (int s = 0; s < 2; ++s) {
        const int k0 = 4 * t + 2 * s, k1 = k0 + 1;
        double fk = (double)f_g[k0],  Rk = (double)R_g[k0];
        double lp = (double)lp_g[k0], bp = (double)bp_g[k0], hp = (double)hp_g[k0];
        double f2 = fk * fk, fbp = fk * bp, flp = f2 * lp, rf2 = 2.0 * Rk * fk;
        const double b0 = flp + fbp + hp, b1 = 2.0 * flp - 2.0 * hp, b2 = flp - fbp + hp;
        const double a0 = f2 + rf2 + 1.0, a1 = 2.0 * f2 - 2.0,       a2 = f2 - rf2 + 1.0;
        fk = (double)f_g[k1];  Rk = (double)R_g[k1];
        lp = (double)lp_g[k1]; bp = (double)bp_g[k1]; hp = (double)hp_g[k1];
        f2 = fk * fk; fbp = fk * bp; flp = f2 * lp; rf2 = 2.0 * Rk * fk;
        const double B0 = flp + fbp + hp, B1 = 2.0 * flp - 2.0 * hp, B2 = flp - fbp + hp;
        const double A0 = f2 + rf2 + 1.0, A1 = 2.0 * f2 - 2.0,       A2 = f2 - rf2 + 1.0;
        qn[s][0] = b0 * B0;
        qn[s][1] = b0 * B1 + b1 * B0;
        qn[s][2] = b0 * B2 + b1 * B1 + b2 * B0;
        qn[s][3] = b1 * B2 + b2 * B1;
        qn[s][4] = b2 * B2;
        qd[s][0] = a0 * A0;
        qd[s][1] = a0 * A1 + a1 * A0;
        qd[s][2] = a0 * A2 + a1 * A1 + a2 * A0;
        qd[s][3] = a1 * A2 + a2 * A1;
        qd[s][4] = a2 * A2;
    }
    double en[9], ed[9];
    for (int j = 0; j < 9; ++j) { en[j] = 0.0; ed[j] = 0.0; }
    for (int i = 0; i < 5; ++i)
        for (int j = 0; j < 5; ++j) {
            en[i + j] += qn[0][i] * qn[1][j];
            ed[i + j] += qd[0][i] * qd[1][j];
        }
    float* cp = coef + t * 18;
    for (int j = 0; j < 9; ++j) {
        cp[j]     = (float)en[j];
        cp[9 + j] = (float)ed[j];
    }
}

__global__ __launch_bounds__(BLOCK) void svf_f32_v12(
    const float* __restrict__ xr_g, const float* __restrict__ xi_g,
    const float* __restrict__ coef,
    float* __restrict__ out, int n, long long cap_floats)
{
    const int t = threadIdx.x;
    const long long base = (long long)(blockIdx.x * BLOCK + t) * MPT;

    float X1r[MPT], X1i[MPT], X2r[MPT], X2i[MPT], X3r[MPT], X3i[MPT];
    float X4r[MPT], X4i[MPT], X5r[MPT], X5i[MPT], X6r[MPT], X6i[MPT];
    float X7r[MPT], X7i[MPT], X8r[MPT], X8i[MPT];
    float Hr[MPT], Hi[MPT];

    if (base + MPT <= (long long)n) {
        const float4 a = *reinterpret_cast<const float4*>(xr_g + base);
        const float4 b = *reinterpret_cast<const float4*>(xi_g + base);
        X1r[0] = a.x; X1r[1] = a.y; X1r[2] = a.z; X1r[3] = a.w;
        X1i[0] = b.x; X1i[1] = b.y; X1i[2] = b.z; X1i[3] = b.w;
    } else {
        for (int m = 0; m < MPT; ++m) {
            const long long idx = base + m;
            const bool ok = idx < (long long)n;
            X1r[m] = ok ? xr_g[idx] : 1.0f;
            X1i[m] = ok ? xi_g[idx] : 0.0f;
        }
    }

    #pragma unroll
    for (int m = 0; m < MPT; ++m) {
        X2r[m] = fmaf(X1r[m], X1r[m], -(X1i[m] * X1i[m]));
        X2i[m] = 2.0f * X1r[m] * X1i[m];
        X3r[m] = fmaf(X2r[m], X1r[m], -(X2i[m] * X1i[m]));
        X3i[m] = fmaf(X2r[m], X1i[m],   X2i[m] * X1r[m]);
        X4r[m] = fmaf(X2r[m], X2r[m], -(X2i[m] * X2i[m]));
        X4i[m] = 2.0f * X2r[m] * X2i[m];
        X5r[m] = fmaf(X4r[m], X1r[m], -(X4i[m] * X1i[m]));
        X5i[m] = fmaf(X4r[m], X1i[m],   X4i[m] * X1r[m]);
        X6r[m] = fmaf(X3r[m], X3r[m], -(X3i[m] * X3i[m]));
        X6i[m] = 2.0f * X3r[m] * X3i[m];
        X7r[m] = fmaf(X4r[m], X3r[m], -(X4i[m] * X3i[m]));
        X7i[m] = fmaf(X4r[m], X3i[m],   X4i[m] * X3r[m]);
        X8r[m] = fmaf(X4r[m], X4r[m], -(X4i[m] * X4i[m]));
        X8i[m] = 2.0f * X4r[m] * X4i[m];
        Hr[m] = 1.0f;   // H starts at (1 + 1j)
        Hi[m] = 1.0f;
    }

    #pragma unroll
    for (int p = 0; p < NOCT; ++p) {
        // Loop-uniform -> s_load; full unroll pipelines coef loads.
        const float* cp = coef + p * 18;
        const float e0 = cp[0], e1 = cp[1], e2 = cp[2], e3 = cp[3], e4 = cp[4];
        const float e5 = cp[5], e6 = cp[6], e7 = cp[7], e8 = cp[8];
        const float g0 = cp[9], g1 = cp[10], g2 = cp[11], g3 = cp[12], g4 = cp[13];
        const float g5 = cp[14], g6 = cp[15], g7 = cp[16], g8 = cp[17];
        #pragma unroll
        for (int m = 0; m < MPT; ++m) {
            // num octic (real coefs, complex powers precomputed)
            const float nr = fmaf(e0, X8r[m], fmaf(e1, X7r[m], fmaf(e2, X6r[m],
                             fmaf(e3, X5r[m], fmaf(e4, X4r[m], fmaf(e5, X3r[m],
                             fmaf(e6, X2r[m], fmaf(e7, X1r[m], e8))))))));
            const float ni = fmaf(e0, X8i[m], fmaf(e1, X7i[m], fmaf(e2, X6i[m],
                             fmaf(e3, X5i[m], fmaf(e4, X4i[m], fmaf(e5, X3i[m],
                             fmaf(e6, X2i[m], e7 * X1i[m])))))));
            // den octic
            const float dr = fmaf(g0, X8r[m], fmaf(g1, X7r[m], fmaf(g2, X6r[m],
                             fmaf(g3, X5r[m], fmaf(g4, X4r[m], fmaf(g5, X3r[m],
                             fmaf(g6, X2r[m], fmaf(g7, X1r[m], g8))))))));
            const float di = fmaf(g0, X8i[m], fmaf(g1, X7i[m], fmaf(g2, X6i[m],
                             fmaf(g3, X5i[m], fmaf(g4, X4i[m], fmaf(g5, X3i[m],
                             fmaf(g6, X2i[m], g7 * X1i[m])))))));
            // ratio = num * conj(den) / |den|^2 (per-stage division)
            const float dd  = fmaf(dr, dr, di * di);
            const float inv = __builtin_amdgcn_rcpf(dd);   // ~1e-7 rel, ok
            const float tr  = fmaf(nr, dr,   ni * di);
            const float ti  = fmaf(ni, dr, -(nr * di));
            const float rr  = tr * inv;
            const float ri  = ti * inv;
            // H *= ratio
            const float hr = fmaf(Hr[m], rr, -(Hi[m] * ri));
            const float hi = fmaf(Hr[m], ri,   Hi[m] * rr);
            Hr[m] = hr; Hi[m] = hi;
        }
    }

    // PLANAR output: out[0..n-1] = Re H, out[n..2n-1] = Im H. Guarded.
    const long long imag_off = (long long)n;
    if (base + MPT <= (long long)n && 2LL * (long long)n <= cap_floats) {
        float4 vr, vi;
        vr.x = Hr[0]; vr.y = Hr[1]; vr.z = Hr[2]; vr.w = Hr[3];
        vi.x = Hi[0]; vi.y = Hi[1]; vi.z = Hi[2]; vi.w = Hi[3];
        *reinterpret_cast<float4*>(out + base)            = vr;
        *reinterpret_cast<float4*>(out + imag_off + base) = vi;
    } else {
        for (int m = 0; m < MPT; ++m) {
            const long long idx = base + m;
            if (idx < (long long)n) {
                if (idx + 1 <= cap_floats) out[idx] = Hr[m];
                const long long oi = imag_off + idx;
                if (oi + 1 <= cap_floats) out[oi] = Hi[m];
            }
        }
    }
}

extern "C" void kernel_launch(void* const* d_in, const int* in_sizes, int n_in,
                              void* d_out, int out_size, void* d_ws, size_t ws_size,
                              hipStream_t stream) {
    const float* xr = (const float*)d_in[0];
    const float* xi = (const float*)d_in[1];
    const float* f  = (const float*)d_in[2];
    const float* R  = (const float*)d_in[3];
    const float* lp = (const float*)d_in[4];
    const float* bp = (const float*)d_in[5];
    const float* hp = (const float*)d_in[6];
    float* out = (float*)d_out;
    float* coef = (float*)d_ws;   // 16*18*4 = 1152 B of scratch

    const int n = in_sizes[0];  // 1048576
    long long cap = (long long)out_size;
    if (cap > 2LL * (long long)n) cap = 2LL * (long long)n;

    // Stage 1: octic coefficients (f64 math, f32 store) into workspace.
    svf_coef_v12<<<1, 64, 0, stream>>>(f, R, lp, bp, hp, coef);
    // Stage 2: main sweep, all-f32, 16 unrolled octic stages, MPT=4.
    const int grid = (n + BLOCK * MPT - 1) / (BLOCK * MPT);  // 1024
    svf_f32_v12<<<grid, BLOCK, 0, stream>>>(xr, xi, coef, out, n, cap);
}

// Round 14
// 83.166 us; speedup vs baseline: 1.1582x; 1.1582x over previous
//
#include <hip/hip_runtime.h>

// SVF cascade frequency response on MI355X (gfx950) — R13.
//
// H(x) = (1+1j) * prod_k (b0*x^2+b1*x+b2)/(a0*x^2+a1*x+a2)
//
// Established: PLANAR output [Re H | Im H]; f32 datapath; octic fusion
// (4 sections/stage, 16 stages; coefs f64-exact -> f32); scalar-path coef
// delivery via d_ws; per-stage division w/ raw v_rcp_f32; guarded stores;
// absmax pinned at 3.814697e-6 (= np ref's own f32 noise) across f64/f32/
// quartic/octic variants.
//
// History: R11 (MPT=2, grid 2048) = 82.3 us bench — best. R12 (MPT=4,
// grid 1024) = 96.3 — VGPR-pressure regression, reverted. Bench anatomy:
// 41 us harness poison fill (83% HBM peak, untouchable) + ~18 us overhead
// + ~3 us coef + ~20 us main kernel (op floor ~10).
//
// R13 = R11 + coef stride padded 18 -> 20 floats (80 B, 16 B-aligned) so
// the unrolled stage coef fetches become clean s_load_dwordx4/x8/x16
// bursts — attacking scalar-fetch lgkmcnt waits, the remaining candidate
// for the ~50% issue gap. Per-sample math bit-identical to R11.

#define NSEC  64
#define NOCT  16
#define CSTRIDE 20   // padded floats per stage (16-byte aligned blocks)
#define BLOCK 256
#define MPT   2      // samples per thread (R11 optimum)

// Pre-kernel: octic (4-section fused) coefficients in f64, stored f32.
// Layout: coef[t*CSTRIDE + 0..8] = num e0..e8 (x^8..x^0),
//         coef[t*CSTRIDE + 9..17] = den e0..e8, [18..19] = pad.
__global__ __launch_bounds__(64) void svf_coef_v13(
    const float* __restrict__ f_g,  const float* __restrict__ R_g,
    const float* __restrict__ lp_g, const float* __restrict__ bp_g,
    const float* __restrict__ hp_g,
    float* __restrict__ coef)
{
    const int t = threadIdx.x;
    if (t >= NOCT) return;

    double qn[2][5], qd[2][5];   // two quartics (pairs of sections)
    for (int s = 0; s < 2; ++s) {
        const int k0 = 4 * t + 2 * s, k1 = k0 + 1;
        double fk = (double)f_g[k0],  Rk = (double)R_g[k0];
        double lp = (double)lp_g[k0], bp = (double)bp_g[k0], hp = (double)hp_g[k0];
        double f2 = fk * fk, fbp = fk * bp, flp = f2 * lp, rf2 = 2.0 * Rk * fk;
        const double b0 = flp + fbp + hp, b1 = 2.0 * flp - 2.0 * hp, b2 = flp - fbp + hp;
        const double a0 = f2 + rf2 + 1.0, a1 = 2.0 * f2 - 2.0,       a2 = f2 - rf2 + 1.0;
        fk = (double)f_g[k1];  Rk = (double)R_g[k1];
        lp = (double)lp_g[k1]; bp = (double)bp_g[k1]; hp = (double)hp_g[k1];
        f2 = fk * fk; fbp = fk * bp; flp = f2 * lp; rf2 = 2.0 * Rk * fk;
        const double B0 = flp + fbp + hp, B1 = 2.0 * flp - 2.0 * hp, B2 = flp - fbp + hp;
        const double A0 = f2 + rf2 + 1.0, A1 = 2.0 * f2 - 2.0,       A2 = f2 - rf2 + 1.0;
        qn[s][0] = b0 * B0;
        qn[s][1] = b0 * B1 + b1 * B0;
        qn[s][2] = b0 * B2 + b1 * B1 + b2 * B0;
        qn[s][3] = b1 * B2 + b2 * B1;
        qn[s][4] = b2 * B2;
        qd[s][0] = a0 * A0;
        qd[s][1] = a0 * A1 + a1 * A0;
        qd[s][2] = a0 * A2 + a1 * A1 + a2 * A0;
        qd[s][3] = a1 * A2 + a2 * A1;
        qd[s][4] = a2 * A2;
    }
    double en[9], ed[9];
    for (int j = 0; j < 9; ++j) { en[j] = 0.0; ed[j] = 0.0; }
    for (int i = 0; i < 5; ++i)
        for (int j = 0; j < 5; ++j) {
            en[i + j] += qn[0][i] * qn[1][j];
            ed[i + j] += qd[0][i] * qd[1][j];
        }
    float* cp = coef + t * CSTRIDE;
    for (int j = 0; j < 9; ++j) {
        cp[j]     = (float)en[j];
        cp[9 + j] = (float)ed[j];
    }
    cp[18] = 0.0f;
    cp[19] = 0.0f;
}

__global__ __launch_bounds__(BLOCK) void svf_f32_v13(
    const float* __restrict__ xr_g, const float* __restrict__ xi_g,
    const float* __restrict__ coef,
    float* __restrict__ out, int n, long long cap_floats)
{
    const int t = threadIdx.x;
    const long long base = (long long)(blockIdx.x * BLOCK + t) * MPT;

    float X1r[MPT], X1i[MPT], X2r[MPT], X2i[MPT], X3r[MPT], X3i[MPT];
    float X4r[MPT], X4i[MPT], X5r[MPT], X5i[MPT], X6r[MPT], X6i[MPT];
    float X7r[MPT], X7i[MPT], X8r[MPT], X8i[MPT];
    float Hr[MPT], Hi[MPT];

    if (base + MPT <= (long long)n) {
        const float2 a = *reinterpret_cast<const float2*>(xr_g + base);
        const float2 b = *reinterpret_cast<const float2*>(xi_g + base);
        X1r[0] = a.x; X1r[1] = a.y;
        X1i[0] = b.x; X1i[1] = b.y;
    } else {
        for (int m = 0; m < MPT; ++m) {
            const long long idx = base + m;
            const bool ok = idx < (long long)n;
            X1r[m] = ok ? xr_g[idx] : 1.0f;
            X1i[m] = ok ? xi_g[idx] : 0.0f;
        }
    }

    #pragma unroll
    for (int m = 0; m < MPT; ++m) {
        X2r[m] = fmaf(X1r[m], X1r[m], -(X1i[m] * X1i[m]));
        X2i[m] = 2.0f * X1r[m] * X1i[m];
        X3r[m] = fmaf(X2r[m], X1r[m], -(X2i[m] * X1i[m]));
        X3i[m] = fmaf(X2r[m], X1i[m],   X2i[m] * X1r[m]);
        X4r[m] = fmaf(X2r[m], X2r[m], -(X2i[m] * X2i[m]));
        X4i[m] = 2.0f * X2r[m] * X2i[m];
        X5r[m] = fmaf(X4r[m], X1r[m], -(X4i[m] * X1i[m]));
        X5i[m] = fmaf(X4r[m], X1i[m],   X4i[m] * X1r[m]);
        X6r[m] = fmaf(X3r[m], X3r[m], -(X3i[m] * X3i[m]));
        X6i[m] = 2.0f * X3r[m] * X3i[m];
        X7r[m] = fmaf(X4r[m], X3r[m], -(X4i[m] * X3i[m]));
        X7i[m] = fmaf(X4r[m], X3i[m],   X4i[m] * X3r[m]);
        X8r[m] = fmaf(X4r[m], X4r[m], -(X4i[m] * X4i[m]));
        X8i[m] = 2.0f * X4r[m] * X4i[m];
        Hr[m] = 1.0f;   // H starts at (1 + 1j)
        Hi[m] = 1.0f;
    }

    #pragma unroll
    for (int p = 0; p < NOCT; ++p) {
        // 16B-aligned 80B block per stage -> clean s_load_dwordx4/x8/x16.
        const float* cp = coef + p * CSTRIDE;
        const float e0 = cp[0], e1 = cp[1], e2 = cp[2], e3 = cp[3], e4 = cp[4];
        const float e5 = cp[5], e6 = cp[6], e7 = cp[7], e8 = cp[8];
        const float g0 = cp[9], g1 = cp[10], g2 = cp[11], g3 = cp[12], g4 = cp[13];
        const float g5 = cp[14], g6 = cp[15], g7 = cp[16], g8 = cp[17];
        #pragma unroll
        for (int m = 0; m < MPT; ++m) {
            // num octic (real coefs, complex powers precomputed)
            const float nr = fmaf(e0, X8r[m], fmaf(e1, X7r[m], fmaf(e2, X6r[m],
                             fmaf(e3, X5r[m], fmaf(e4, X4r[m], fmaf(e5, X3r[m],
                             fmaf(e6, X2r[m], fmaf(e7, X1r[m], e8))))))));
            const float ni = fmaf(e0, X8i[m], fmaf(e1, X7i[m], fmaf(e2, X6i[m],
                             fmaf(e3, X5i[m], fmaf(e4, X4i[m], fmaf(e5, X3i[m],
                             fmaf(e6, X2i[m], e7 * X1i[m])))))));
            // den octic
            const float dr = fmaf(g0, X8r[m], fmaf(g1, X7r[m], fmaf(g2, X6r[m],
                             fmaf(g3, X5r[m], fmaf(g4, X4r[m], fmaf(g5, X3r[m],
                             fmaf(g6, X2r[m], fmaf(g7, X1r[m], g8))))))));
            const float di = fmaf(g0, X8i[m], fmaf(g1, X7i[m], fmaf(g2, X6i[m],
                             fmaf(g3, X5i[m], fmaf(g4, X4i[m], fmaf(g5, X3i[m],
                             fmaf(g6, X2i[m], g7 * X1i[m])))))));
            // ratio = num * conj(den) / |den|^2 (per-stage division)
            const float dd  = fmaf(dr, dr, di * di);
            const float inv = __builtin_amdgcn_rcpf(dd);   // ~1e-7 rel, ok
            const float tr  = fmaf(nr, dr,   ni * di);
            const float ti  = fmaf(ni, dr, -(nr * di));
            const float rr  = tr * inv;
            const float ri  = ti * inv;
            // H *= ratio
            const float hr = fmaf(Hr[m], rr, -(Hi[m] * ri));
            const float hi = fmaf(Hr[m], ri,   Hi[m] * rr);
            Hr[m] = hr; Hi[m] = hi;
        }
    }

    // PLANAR output: out[0..n-1] = Re H, out[n..2n-1] = Im H. Guarded.
    const long long imag_off = (long long)n;
    if (base + MPT <= (long long)n && 2LL * (long long)n <= cap_floats) {
        float2 vr, vi;
        vr.x = Hr[0]; vr.y = Hr[1];
        vi.x = Hi[0]; vi.y = Hi[1];
        *reinterpret_cast<float2*>(out + base)            = vr;
        *reinterpret_cast<float2*>(out + imag_off + base) = vi;
    } else {
        for (int m = 0; m < MPT; ++m) {
            const long long idx = base + m;
            if (idx < (long long)n) {
                if (idx + 1 <= cap_floats) out[idx] = Hr[m];
                const long long oi = imag_off + idx;
                if (oi + 1 <= cap_floats) out[oi] = Hi[m];
            }
        }
    }
}

extern "C" void kernel_launch(void* const* d_in, const int* in_sizes, int n_in,
                              void* d_out, int out_size, void* d_ws, size_t ws_size,
                              hipStream_t stream) {
    const float* xr = (const float*)d_in[0];
    const float* xi = (const float*)d_in[1];
    const float* f  = (const float*)d_in[2];
    const float* R  = (const float*)d_in[3];
    const float* lp = (const float*)d_in[4];
    const float* bp = (const float*)d_in[5];
    const float* hp = (const float*)d_in[6];
    float* out = (float*)d_out;
    float* coef = (float*)d_ws;   // 16*20*4 = 1280 B of scratch

    const int n = in_sizes[0];  // 1048576
    long long cap = (long long)out_size;
    if (cap > 2LL * (long long)n) cap = 2LL * (long long)n;

    // Stage 1: octic coefficients (f64 math, f32 store) into workspace.
    svf_coef_v13<<<1, 64, 0, stream>>>(f, R, lp, bp, hp, coef);
    // Stage 2: main sweep — R11 optimum: MPT=2, grid 2048.
    const int grid = (n + BLOCK * MPT - 1) / (BLOCK * MPT);  // 2048
    svf_f32_v13<<<grid, BLOCK, 0, stream>>>(xr, xi, coef, out, n, cap);
}

// Round 16
// 82.750 us; speedup vs baseline: 1.1641x; 1.0050x over previous
//
#include <hip/hip_runtime.h>

// SVF cascade frequency response on MI355X (gfx950) — R15 (= R13, final).
//
// H(x) = (1+1j) * prod_k (b0+b1/x+b2/x^2)/(a0+a1/x+a2/x^2)
//      = (1+1j) * prod_k (b0*x^2+b1*x+b2)/(a0*x^2+a1*x+a2)
//
// Final configuration (proven 5/5 green incl. post-timing re-validation):
//  - PLANAR output [Re H | Im H] (R4), all stores guarded (R0/R5 aborts).
//  - f32 datapath (R10: np ref is itself f32-computed; absmax 3.81e-6 is
//    the REF's noise, threshold 1.074e-4 -> 28x margin).
//  - Octic fusion: 4 sections/stage, 16 stages of degree-8 real-coef
//    rationals; powers x..x^8 precomputed per sample (R11).
//  - Coefs computed f64-exact in a tiny PRE-KERNEL, rounded once to f32
//    in d_ws; main kernel reads them via loop-uniform s_loads (R9/R13).
//    (In-kernel coef builds — R4/R14 — failed post-timing; never fuse.)
//  - Per-stage division via raw v_rcp_f32 (R11); MPT=2, grid 2048 (R8/R12
//    showed MPT=4 regresses on VGPR pressure).
//
// Bench anatomy at 82-83 us: ~41 us harness 268MB poison fill (80-84% of
// HBM peak — harness is memory-roofline-bound), ~18 us restore/replay
// overhead, ~3 us coef pre-kernel, ~20 us main kernel (op floor ~10 us;
// 55-65% issue plateau robust vs occupancy/ILP/s_load-alignment attacks).

#define NSEC  64
#define NOCT  16
#define CSTRIDE 20   // padded floats per stage (16-byte aligned blocks)
#define BLOCK 256
#define MPT   2      // samples per thread

// Pre-kernel: octic (4-section fused) coefficients in f64, stored f32.
// Layout: coef[t*CSTRIDE + 0..8] = num e0..e8 (x^8..x^0),
//         coef[t*CSTRIDE + 9..17] = den e0..e8, [18..19] = pad.
__global__ __launch_bounds__(64) void svf_coef_v15(
    const float* __restrict__ f_g,  const float* __restrict__ R_g,
    const float* __restrict__ lp_g, const float* __restrict__ bp_g,
    const float* __restrict__ hp_g,
    float* __restrict__ coef)
{
    const int t = threadIdx.x;
    if (t >= NOCT) return;

    double qn[2][5], qd[2][5];   // two quartics (pairs of sections)
    for (int s = 0; s < 2; ++s) {
        const int k0 = 4 * t + 2 * s, k1 = k0 + 1;
        double fk = (double)f_g[k0],  Rk = (double)R_g[k0];
        double lp = (double)lp_g[k0], bp = (double)bp_g[k0], hp = (double)hp_g[k0];
        double f2 = fk * fk, fbp = fk * bp, flp = f2 * lp, rf2 = 2.0 * Rk * fk;
        const double b0 = flp + fbp + hp, b1 = 2.0 * flp - 2.0 * hp, b2 = flp - fbp + hp;
        const double a0 = f2 + rf2 + 1.0, a1 = 2.0 * f2 - 2.0,       a2 = f2 - rf2 + 1.0;
        fk = (double)f_g[k1];  Rk = (double)R_g[k1];
        lp = (double)lp_g[k1]; bp = (double)bp_g[k1]; hp = (double)hp_g[k1];
        f2 = fk * fk; fbp = fk * bp; flp = f2 * lp; rf2 = 2.0 * Rk * fk;
        const double B0 = flp + fbp + hp, B1 = 2.0 * flp - 2.0 * hp, B2 = flp - fbp + hp;
        const double A0 = f2 + rf2 + 1.0, A1 = 2.0 * f2 - 2.0,       A2 = f2 - rf2 + 1.0;
        qn[s][0] = b0 * B0;
        qn[s][1] = b0 * B1 + b1 * B0;
        qn[s][2] = b0 * B2 + b1 * B1 + b2 * B0;
        qn[s][3] = b1 * B2 + b2 * B1;
        qn[s][4] = b2 * B2;
        qd[s][0] = a0 * A0;
        qd[s][1] = a0 * A1 + a1 * A0;
        qd[s][2] = a0 * A2 + a1 * A1 + a2 * A0;
        qd[s][3] = a1 * A2 + a2 * A1;
        qd[s][4] = a2 * A2;
    }
    double en[9], ed[9];
    for (int j = 0; j < 9; ++j) { en[j] = 0.0; ed[j] = 0.0; }
    for (int i = 0; i < 5; ++i)
        for (int j = 0; j < 5; ++j) {
            en[i + j] += qn[0][i] * qn[1][j];
            ed[i + j] += qd[0][i] * qd[1][j];
        }
    float* cp = coef + t * CSTRIDE;
    for (int j = 0; j < 9; ++j) {
        cp[j]     = (float)en[j];
        cp[9 + j] = (float)ed[j];
    }
    cp[18] = 0.0f;
    cp[19] = 0.0f;
}

__global__ __launch_bounds__(BLOCK) void svf_f32_v15(
    const float* __restrict__ xr_g, const float* __restrict__ xi_g,
    const float* __restrict__ coef,
    float* __restrict__ out, int n, long long cap_floats)
{
    const int t = threadIdx.x;
    const long long base = (long long)(blockIdx.x * BLOCK + t) * MPT;

    float X1r[MPT], X1i[MPT], X2r[MPT], X2i[MPT], X3r[MPT], X3i[MPT];
    float X4r[MPT], X4i[MPT], X5r[MPT], X5i[MPT], X6r[MPT], X6i[MPT];
    float X7r[MPT], X7i[MPT], X8r[MPT], X8i[MPT];
    float Hr[MPT], Hi[MPT];

    if (base + MPT <= (long long)n) {
        const float2 a = *reinterpret_cast<const float2*>(xr_g + base);
        const float2 b = *reinterpret_cast<const float2*>(xi_g + base);
        X1r[0] = a.x; X1r[1] = a.y;
        X1i[0] = b.x; X1i[1] = b.y;
    } else {
        for (int m = 0; m < MPT; ++m) {
            const long long idx = base + m;
            const bool ok = idx < (long long)n;
            X1r[m] = ok ? xr_g[idx] : 1.0f;
            X1i[m] = ok ? xi_g[idx] : 0.0f;
        }
    }

    #pragma unroll
    for (int m = 0; m < MPT; ++m) {
        X2r[m] = fmaf(X1r[m], X1r[m], -(X1i[m] * X1i[m]));
        X2i[m] = 2.0f * X1r[m] * X1i[m];
        X3r[m] = fmaf(X2r[m], X1r[m], -(X2i[m] * X1i[m]));
        X3i[m] = fmaf(X2r[m], X1i[m],   X2i[m] * X1r[m]);
        X4r[m] = fmaf(X2r[m], X2r[m], -(X2i[m] * X2i[m]));
        X4i[m] = 2.0f * X2r[m] * X2i[m];
        X5r[m] = fmaf(X4r[m], X1r[m], -(X4i[m] * X1i[m]));
        X5i[m] = fmaf(X4r[m], X1i[m],   X4i[m] * X1r[m]);
        X6r[m] = fmaf(X3r[m], X3r[m], -(X3i[m] * X3i[m]));
        X6i[m] = 2.0f * X3r[m] * X3i[m];
        X7r[m] = fmaf(X4r[m], X3r[m], -(X4i[m] * X3i[m]));
        X7i[m] = fmaf(X4r[m], X3i[m],   X4i[m] * X3r[m]);
        X8r[m] = fmaf(X4r[m], X4r[m], -(X4i[m] * X4i[m]));
        X8i[m] = 2.0f * X4r[m] * X4i[m];
        Hr[m] = 1.0f;   // H starts at (1 + 1j)
        Hi[m] = 1.0f;
    }

    #pragma unroll
    for (int p = 0; p < NOCT; ++p) {
        // Loop-uniform -> s_load bursts from 16B-aligned 80B blocks.
        const float* cp = coef + p * CSTRIDE;
        const float e0 = cp[0], e1 = cp[1], e2 = cp[2], e3 = cp[3], e4 = cp[4];
        const float e5 = cp[5], e6 = cp[6], e7 = cp[7], e8 = cp[8];
        const float g0 = cp[9], g1 = cp[10], g2 = cp[11], g3 = cp[12], g4 = cp[13];
        const float g5 = cp[14], g6 = cp[15], g7 = cp[16], g8 = cp[17];
        #pragma unroll
        for (int m = 0; m < MPT; ++m) {
            // num octic (real coefs, complex powers precomputed)
            const float nr = fmaf(e0, X8r[m], fmaf(e1, X7r[m], fmaf(e2, X6r[m],
                             fmaf(e3, X5r[m], fmaf(e4, X4r[m], fmaf(e5, X3r[m],
                             fmaf(e6, X2r[m], fmaf(e7, X1r[m], e8))))))));
            const float ni = fmaf(e0, X8i[m], fmaf(e1, X7i[m], fmaf(e2, X6i[m],
                             fmaf(e3, X5i[m], fmaf(e4, X4i[m], fmaf(e5, X3i[m],
                             fmaf(e6, X2i[m], e7 * X1i[m])))))));
            // den octic
            const float dr = fmaf(g0, X8r[m], fmaf(g1, X7r[m], fmaf(g2, X6r[m],
                             fmaf(g3, X5r[m], fmaf(g4, X4r[m], fmaf(g5, X3r[m],
                             fmaf(g6, X2r[m], fmaf(g7, X1r[m], g8))))))));
            const float di = fmaf(g0, X8i[m], fmaf(g1, X7i[m], fmaf(g2, X6i[m],
                             fmaf(g3, X5i[m], fmaf(g4, X4i[m], fmaf(g5, X3i[m],
                             fmaf(g6, X2i[m], g7 * X1i[m])))))));
            // ratio = num * conj(den) / |den|^2 (per-stage division)
            const float dd  = fmaf(dr, dr, di * di);
            const float inv = __builtin_amdgcn_rcpf(dd);   // ~1e-7 rel, ok
            const float tr  = fmaf(nr, dr,   ni * di);
            const float ti  = fmaf(ni, dr, -(nr * di));
            const float rr  = tr * inv;
            const float ri  = ti * inv;
            // H *= ratio
            const float hr = fmaf(Hr[m], rr, -(Hi[m] * ri));
            const float hi = fmaf(Hr[m], ri,   Hi[m] * rr);
            Hr[m] = hr; Hi[m] = hi;
        }
    }

    // PLANAR output: out[0..n-1] = Re H, out[n..2n-1] = Im H. Guarded.
    const long long imag_off = (long long)n;
    if (base + MPT <= (long long)n && 2LL * (long long)n <= cap_floats) {
        float2 vr, vi;
        vr.x = Hr[0]; vr.y = Hr[1];
        vi.x = Hi[0]; vi.y = Hi[1];
        *reinterpret_cast<float2*>(out + base)            = vr;
        *reinterpret_cast<float2*>(out + imag_off + base) = vi;
    } else {
        for (int m = 0; m < MPT; ++m) {
            const long long idx = base + m;
            if (idx < (long long)n) {
                if (idx + 1 <= cap_floats) out[idx] = Hr[m];
                const long long oi = imag_off + idx;
                if (oi + 1 <= cap_floats) out[oi] = Hi[m];
            }
        }
    }
}

extern "C" void kernel_launch(void* const* d_in, const int* in_sizes, int n_in,
                              void* d_out, int out_size, void* d_ws, size_t ws_size,
                              hipStream_t stream) {
    const float* xr = (const float*)d_in[0];
    const float* xi = (const float*)d_in[1];
    const float* f  = (const float*)d_in[2];
    const float* R  = (const float*)d_in[3];
    const float* lp = (const float*)d_in[4];
    const float* bp = (const float*)d_in[5];
    const float* hp = (const float*)d_in[6];
    float* out = (float*)d_out;
    float* coef = (float*)d_ws;   // 16*20*4 = 1280 B of scratch

    const int n = in_sizes[0];  // 1048576
    long long cap = (long long)out_size;
    if (cap > 2LL * (long long)n) cap = 2LL * (long long)n;

    // Stage 1: octic coefficients (f64 math, f32 store) into workspace.
    svf_coef_v15<<<1, 64, 0, stream>>>(f, R, lp, bp, hp, coef);
    // Stage 2: main sweep — MPT=2, grid 2048 (proven optimum).
    const int grid = (n + BLOCK * MPT - 1) / (BLOCK * MPT);  // 2048
    svf_f32_v15<<<grid, BLOCK, 0, stream>>>(xr, xi, coef, out, n, cap);
}